// Round 1
// baseline (318.930 us; speedup 1.0000x reference)
//
#include <hip/hip_runtime.h>

// Problem constants
#define NROWS   131072          // 32*64*64 points
#define DIM     64
#define KCODES  512
#define BHW     262144          // 64*64*64 elems per batch in NCHW (C*H*W)
#define OUT_Q_OFF 1
#define OUT_P_OFF 8388609       // 1 + 32*64*64*64
#define OUT_E_OFF 8388610

// ws layout (4-byte units): [0] loss accum (f32), [1..513) counts (u32), [513..1025) wsq (f32)

__global__ __launch_bounds__(512) void vq_init(const float* __restrict__ W, float* __restrict__ ws) {
    const int k = threadIdx.x;          // 512 threads, one per code
    const float4* W4 = (const float4*)W;
    float s = 0.f;
#pragma unroll
    for (int i = 0; i < 16; ++i) {
        float4 v = W4[k * 16 + i];
        s = fmaf(v.x, v.x, s);
        s = fmaf(v.y, v.y, s);
        s = fmaf(v.z, v.z, s);
        s = fmaf(v.w, v.w, s);
    }
    ws[513 + k] = s;
}

__global__ __launch_bounds__(256) void vq_main(const float* __restrict__ X,
                                               const float* __restrict__ W,
                                               float* __restrict__ out,
                                               float* ws) {
    const int t   = threadIdx.x;
    const int row = blockIdx.x * 256 + t;
    const int w   = row & 63;
    const int h   = (row >> 6) & 63;
    const int b   = row >> 12;

    // ---- load this row (gather over C, lane-coalesced over w) ----
    const float* xb = X + (size_t)b * BHW + (size_t)h * 64 + w;
    float4 x4[16];
#pragma unroll
    for (int i = 0; i < 16; ++i) {
        x4[i].x = xb[(size_t)(4 * i + 0) * 4096];
        x4[i].y = xb[(size_t)(4 * i + 1) * 4096];
        x4[i].z = xb[(size_t)(4 * i + 2) * 4096];
        x4[i].w = xb[(size_t)(4 * i + 3) * 4096];
    }

    // ---- argmin over codes; W via wave-uniform (scalar) loads ----
    const float4* __restrict__ W4 = (const float4*)W;
    const float*  wsq = ws + 513;
    float bestS = 3.4e38f;
    int   bestk = 0;
#pragma unroll 1
    for (int k = 0; k < KCODES; k += 4) {
        float acc0 = 0.f, acc1 = 0.f, acc2 = 0.f, acc3 = 0.f;
#pragma unroll
        for (int i = 0; i < 16; ++i) {
            float4 xv = x4[i];
            float4 w0 = W4[(k + 0) * 16 + i];
            float4 w1 = W4[(k + 1) * 16 + i];
            float4 w2 = W4[(k + 2) * 16 + i];
            float4 w3 = W4[(k + 3) * 16 + i];
            acc0 = fmaf(w0.x, xv.x, acc0); acc0 = fmaf(w0.y, xv.y, acc0);
            acc0 = fmaf(w0.z, xv.z, acc0); acc0 = fmaf(w0.w, xv.w, acc0);
            acc1 = fmaf(w1.x, xv.x, acc1); acc1 = fmaf(w1.y, xv.y, acc1);
            acc1 = fmaf(w1.z, xv.z, acc1); acc1 = fmaf(w1.w, xv.w, acc1);
            acc2 = fmaf(w2.x, xv.x, acc2); acc2 = fmaf(w2.y, xv.y, acc2);
            acc2 = fmaf(w2.z, xv.z, acc2); acc2 = fmaf(w2.w, xv.w, acc2);
            acc3 = fmaf(w3.x, xv.x, acc3); acc3 = fmaf(w3.y, xv.y, acc3);
            acc3 = fmaf(w3.z, xv.z, acc3); acc3 = fmaf(w3.w, xv.w, acc3);
        }
        float s0 = wsq[k + 0] - 2.f * acc0;
        float s1 = wsq[k + 1] - 2.f * acc1;
        float s2 = wsq[k + 2] - 2.f * acc2;
        float s3 = wsq[k + 3] - 2.f * acc3;
        if (s0 < bestS) { bestS = s0; bestk = k + 0; }
        if (s1 < bestS) { bestS = s1; bestk = k + 1; }
        if (s2 < bestS) { bestS = s2; bestk = k + 2; }
        if (s3 < bestS) { bestS = s3; bestk = k + 3; }
    }

    __shared__ int      best_lds[256];
    __shared__ unsigned hist[512];
    __shared__ float    red[4];

    hist[t] = 0u;
    hist[t + 256] = 0u;
    best_lds[t] = bestk;
    __syncthreads();
    atomicAdd(&hist[bestk], 1u);

    // ---- quantized_st = x + (q - x); loss partial ----
    float lsum = 0.f;
    float* out1 = out + OUT_Q_OFF;
    size_t obase = (size_t)b * BHW + (size_t)h * 64 + w;
#pragma unroll
    for (int i = 0; i < 16; ++i) {
        float4 q  = W4[bestk * 16 + i];   // divergent gather, L2-resident
        float4 xv = x4[i];
        float d0 = q.x - xv.x, d1 = q.y - xv.y, d2 = q.z - xv.z, d3 = q.w - xv.w;
        lsum = fmaf(d0, d0, lsum); lsum = fmaf(d1, d1, lsum);
        lsum = fmaf(d2, d2, lsum); lsum = fmaf(d3, d3, lsum);
        out1[obase + (size_t)(4 * i + 0) * 4096] = xv.x + d0;
        out1[obase + (size_t)(4 * i + 1) * 4096] = xv.y + d1;
        out1[obase + (size_t)(4 * i + 2) * 4096] = xv.z + d2;
        out1[obase + (size_t)(4 * i + 3) * 4096] = xv.w + d3;
    }
#pragma unroll
    for (int off = 32; off >= 1; off >>= 1) lsum += __shfl_down(lsum, off);
    if ((t & 63) == 0) red[t >> 6] = lsum;
    __syncthreads();   // also orders hist atomics before readback
    if (t == 0) atomicAdd(ws, red[0] + red[1] + red[2] + red[3]);

    unsigned c0 = hist[t], c1 = hist[t + 256];
    unsigned* gcounts = (unsigned*)ws + 1;
    if (c0) atomicAdd(gcounts + t, c0);
    if (c1) atomicAdd(gcounts + t + 256, c1);

    // ---- one-hot encodings, cooperative fully-coalesced writes ----
    // region starts at element 8388610 -> only 8B aligned -> float2 stores
    const int base = blockIdx.x * 256;
    float2* enc2 = (float2*)(out + OUT_E_OFF);
#pragma unroll 1
    for (int r = 0; r < 256; ++r) {
        int bk = best_lds[r];
        float2 v = make_float2(0.f, 0.f);
        if ((bk >> 1) == t) { if (bk & 1) v.y = 1.f; else v.x = 1.f; }
        enc2[(((size_t)(base + r)) << 8) + t] = v;
    }
}

__global__ __launch_bounds__(512) void vq_fin(const float* __restrict__ ws, float* __restrict__ out) {
    __shared__ float red[8];
    const int t = threadIdx.x;   // 512 threads, one per code
    const unsigned* counts = (const unsigned*)ws + 1;
    float p = (float)counts[t] * (1.0f / 131072.0f);
    float s = p * logf(p + 1e-10f);
#pragma unroll
    for (int off = 32; off >= 1; off >>= 1) s += __shfl_down(s, off);
    if ((t & 63) == 0) red[t >> 6] = s;
    __syncthreads();
    if (t == 0) {
        float tot = 0.f;
#pragma unroll
        for (int i = 0; i < 8; ++i) tot += red[i];
        out[OUT_P_OFF] = expf(-tot);
        out[0] = ws[0] * (1.25f / 8388608.0f);
    }
}

extern "C" void kernel_launch(void* const* d_in, const int* in_sizes, int n_in,
                              void* d_out, int out_size, void* d_ws, size_t ws_size,
                              hipStream_t stream) {
    const float* X = (const float*)d_in[0];   // (32, 64, 64, 64) f32, NCHW
    const float* W = (const float*)d_in[1];   // (512, 64) f32
    float* out = (float*)d_out;
    float* ws  = (float*)d_ws;

    // zero loss accumulator + counts every call (ws not re-poisoned between replays,
    // but we must not rely on leftover state either way)
    hipMemsetAsync(d_ws, 0, 513 * sizeof(float), stream);
    vq_init<<<1, 512, 0, stream>>>(W, ws);
    vq_main<<<512, 256, 0, stream>>>(X, W, out, ws);
    vq_fin<<<1, 512, 0, stream>>>(ws, out);
}

// Round 2
// 112.663 us; speedup vs baseline: 2.8308x; 2.8308x over previous
//
#include <hip/hip_runtime.h>

// Problem: VQ-VAE vector quantizer. N=131072 rows (32*64*64), D=64, K=512.
// X is NCHW f32 (32,64,64,64); W is (512,64) f32.
// out: [0]=loss, [1..8388609)=quantized NCHW, [8388609]=perplexity,
//      [8388610..)=one-hot encodings [131072][512].
#define BHW 262144
#define OUT_Q_OFF 1
#define OUT_P_OFF 8388609
#define OUT_E_OFF 8388610

// ws layout (4-byte words):
// [0]         loss accumulator (f32)
// [1..513)    counts (u32)
// [513..1025) wsq = ||e_k||^2 (f32)
// [1032..17416) pre-swizzled bf16 codebook B-fragments: [tn=32][j=2][lane=64] x 8 bf16

typedef __attribute__((ext_vector_type(8))) short short8;
typedef __attribute__((ext_vector_type(4))) float f32x4;

__device__ __forceinline__ unsigned short f2bf(float f) {
    union { float f; unsigned u; } c; c.f = f;
    unsigned r = (c.u + 0x7FFFu + ((c.u >> 16) & 1u)) >> 16;  // RNE
    return (unsigned short)r;
}

__global__ __launch_bounds__(512) void vq_init(const float* __restrict__ W, float* __restrict__ ws) {
    const int tid = blockIdx.x * 512 + threadIdx.x;
    if (tid < 512) {
        // wsq[k] = ||e_k||^2
        const float4* W4 = (const float4*)W;
        float s = 0.f;
#pragma unroll
        for (int i = 0; i < 16; ++i) {
            float4 v = W4[tid * 16 + i];
            s = fmaf(v.x, v.x, s); s = fmaf(v.y, v.y, s);
            s = fmaf(v.z, v.z, s); s = fmaf(v.w, v.w, s);
        }
        ws[513 + tid] = s;
    } else {
        // B-fragment pre-swizzle: chunk c -> (tn, j, lane); 8 bf16 = one lane's frag half
        const int c  = tid - 512;            // 0..4095
        const int l  = c & 63;
        const int j  = (c >> 6) & 1;
        const int tn = c >> 7;
        const int n  = tn * 16 + (l & 15);
        const int k0 = j * 32 + ((l >> 4) & 3) * 8;
        const float* src = W + n * 64 + k0;  // 8 consecutive dims
        unsigned h0 = f2bf(src[0]) | ((unsigned)f2bf(src[1]) << 16);
        unsigned h1 = f2bf(src[2]) | ((unsigned)f2bf(src[3]) << 16);
        unsigned h2 = f2bf(src[4]) | ((unsigned)f2bf(src[5]) << 16);
        unsigned h3 = f2bf(src[6]) | ((unsigned)f2bf(src[7]) << 16);
        uint4* dst = (uint4*)(ws + 1032);
        dst[c] = make_uint4(h0, h1, h2, h3);
    }
}

__global__ __launch_bounds__(256) void vq_main(const float* __restrict__ X,
                                               const float* __restrict__ W,
                                               float* __restrict__ out,
                                               float* __restrict__ ws) {
    const int t    = threadIdx.x;
    const int l    = t & 63;
    const int wv   = t >> 6;
    const int nlow = l & 15;
    const int kg   = l >> 4;                 // 0..3 lane group
    const int rowbase = blockIdx.x * 64;     // 64 rows per block, all share (b,h)
    const int b = rowbase >> 12;
    const int h = (rowbase >> 6) & 63;

    __shared__ int   best_lds[64];
    __shared__ float qlds[64][65];           // +1 pad: LDS bank-conflict-free column reads
    __shared__ float red[4];

    // ---- A fragments: this wave's 16 rows (w = wv*16 + nlow), k via (kg,slot) ----
    const float* xrow = X + (size_t)b * BHW + (size_t)h * 64 + wv * 16 + nlow;
    short8 a0, a1;
    {
        float tmp[16];
#pragma unroll
        for (int e = 0; e < 8; ++e) tmp[e]     = xrow[(size_t)(kg * 8 + e) * 4096];
#pragma unroll
        for (int e = 0; e < 8; ++e) tmp[8 + e] = xrow[(size_t)(32 + kg * 8 + e) * 4096];
#pragma unroll
        for (int e = 0; e < 8; ++e) { a0[e] = (short)f2bf(tmp[e]); a1[e] = (short)f2bf(tmp[8 + e]); }
    }

    // ---- scores for 16 rows x 512 codes via MFMA; running argmin ----
    const short8* __restrict__ B8  = (const short8*)(ws + 1032);
    const float*  __restrict__ wsq = ws + 513;
    float bS0 = 3.4e38f, bS1 = 3.4e38f, bS2 = 3.4e38f, bS3 = 3.4e38f;
    int   bK0 = 0, bK1 = 0, bK2 = 0, bK3 = 0;
#pragma unroll 2
    for (int tn = 0; tn < 32; ++tn) {
        short8 f0 = B8[tn * 128 + l];
        short8 f1 = B8[tn * 128 + 64 + l];
        f32x4 acc = {0.f, 0.f, 0.f, 0.f};
        acc = __builtin_amdgcn_mfma_f32_16x16x32_bf16(a0, f0, acc, 0, 0, 0);
        acc = __builtin_amdgcn_mfma_f32_16x16x32_bf16(a1, f1, acc, 0, 0, 0);
        const int   n  = tn * 16 + nlow;
        const float wq = wsq[n];
        float s;
        s = fmaf(-2.f, acc[0], wq); if (s < bS0) { bS0 = s; bK0 = n; }
        s = fmaf(-2.f, acc[1], wq); if (s < bS1) { bS1 = s; bK1 = n; }
        s = fmaf(-2.f, acc[2], wq); if (s < bS2) { bS2 = s; bK2 = n; }
        s = fmaf(-2.f, acc[3], wq); if (s < bS3) { bS3 = s; bK3 = n; }
    }
    // min-reduce across the 16 n-lanes (same kg group); lowest-index tiebreak (np argmin)
#pragma unroll
    for (int mask = 1; mask <= 8; mask <<= 1) {
        float oS; int oK;
        oS = __shfl_xor(bS0, mask); oK = __shfl_xor(bK0, mask);
        if (oS < bS0 || (oS == bS0 && oK < bK0)) { bS0 = oS; bK0 = oK; }
        oS = __shfl_xor(bS1, mask); oK = __shfl_xor(bK1, mask);
        if (oS < bS1 || (oS == bS1 && oK < bK1)) { bS1 = oS; bK1 = oK; }
        oS = __shfl_xor(bS2, mask); oK = __shfl_xor(bK2, mask);
        if (oS < bS2 || (oS == bS2 && oK < bK2)) { bS2 = oS; bK2 = oK; }
        oS = __shfl_xor(bS3, mask); oK = __shfl_xor(bK3, mask);
        if (oS < bS3 || (oS == bS3 && oK < bK3)) { bS3 = oS; bK3 = oK; }
    }
    if (nlow == 0) {
        // D rows: m_local = kg*4 + reg  (m89-verified C/D layout)
        best_lds[wv * 16 + kg * 4 + 0] = bK0;
        best_lds[wv * 16 + kg * 4 + 1] = bK1;
        best_lds[wv * 16 + kg * 4 + 2] = bK2;
        best_lds[wv * 16 + kg * 4 + 3] = bK3;
    }
    __syncthreads();

    // ---- stage selected code rows into LDS (f32); histogram atomics ----
#pragma unroll
    for (int i = 0; i < 16; ++i) {
        int e = i * 256 + t;
        int row = e >> 6, d = e & 63;        // row uniform per wave per i -> coalesced W read
        qlds[row][d] = W[best_lds[row] * 64 + d];
    }
    if (t < 64) atomicAdd((unsigned*)ws + 1 + best_lds[t], 1u);
    __syncthreads();

    // ---- quantized_st + loss partials ----
    const int dg = t >> 6;
    const int wq_ = t & 63;
    float lsum = 0.f;
    {
        const size_t base = (size_t)b * BHW + (size_t)h * 64 + wq_;
        const float* xp = X + base;
        float* op = out + OUT_Q_OFF + base;
#pragma unroll
        for (int i = 0; i < 16; ++i) {
            int d = dg * 16 + i;
            float x = xp[(size_t)d * 4096];
            float q = qlds[wq_][d];
            float diff = q - x;
            lsum = fmaf(diff, diff, lsum);
            op[(size_t)d * 4096] = x + diff;
        }
    }

    // ---- one-hot encodings (fully coalesced float2 stores; region only 8B-aligned) ----
    float2* enc2 = (float2*)(out + OUT_E_OFF);
    const size_t ebase = ((size_t)rowbase) << 8;
#pragma unroll 1
    for (int i = 0; i < 64; ++i) {
        int bk = best_lds[i];
        float2 v;
        v.x = (bk == 2 * t)     ? 1.f : 0.f;
        v.y = (bk == 2 * t + 1) ? 1.f : 0.f;
        enc2[ebase + ((size_t)i << 8) + t] = v;
    }

    // ---- loss reduction ----
#pragma unroll
    for (int off = 32; off >= 1; off >>= 1) lsum += __shfl_down(lsum, off);
    if (l == 0) red[wv] = lsum;
    __syncthreads();
    if (t == 0) atomicAdd(ws, red[0] + red[1] + red[2] + red[3]);
}

__global__ __launch_bounds__(512) void vq_fin(const float* __restrict__ ws, float* __restrict__ out) {
    __shared__ float red[8];
    const int t = threadIdx.x;
    const unsigned* counts = (const unsigned*)ws + 1;
    float p = (float)counts[t] * (1.0f / 131072.0f);
    float s = p * logf(p + 1e-10f);
#pragma unroll
    for (int off = 32; off >= 1; off >>= 1) s += __shfl_down(s, off);
    if ((t & 63) == 0) red[t >> 6] = s;
    __syncthreads();
    if (t == 0) {
        float tot = 0.f;
#pragma unroll
        for (int i = 0; i < 8; ++i) tot += red[i];
        out[OUT_P_OFF] = expf(-tot);
        out[0] = ws[0] * (1.25f / 8388608.0f);
    }
}

extern "C" void kernel_launch(void* const* d_in, const int* in_sizes, int n_in,
                              void* d_out, int out_size, void* d_ws, size_t ws_size,
                              hipStream_t stream) {
    const float* X = (const float*)d_in[0];
    const float* W = (const float*)d_in[1];
    float* out = (float*)d_out;
    float* ws  = (float*)d_ws;

    hipMemsetAsync(d_ws, 0, 513 * sizeof(float), stream);   // loss + counts
    vq_init<<<9, 512, 0, stream>>>(W, ws);
    vq_main<<<2048, 256, 0, stream>>>(X, W, out, ws);
    vq_fin<<<1, 512, 0, stream>>>(ws, out);
}